// Round 2
// baseline (1713.277 us; speedup 1.0000x reference)
//
#include <hip/hip_runtime.h>

// GraphRefiner: Fused = LN1(Z + beta*Y); graph = exact kNN(k) row-normalized
// adjacency from Fused; hidden = LN2(mean_nbr(Fused) @ W^T + bias).
//
// Strategy: fp32 pass-1 distances into the graph output region (overwritten by
// top-k), fp64 refinement for rows with ambiguous 16/17 boundary (gap < TAU).
// LN1 keeps an fp64 copy of Fused in ws so refined distances match an fp64
// numpy reference to ~1e-12.

#define TAU 0.01f
#define CAP 256      // max refined rows (expected ~4 at TAU=0.01)
#define KMAX 64

// ---------------- block-wide f64 sum over 128 threads (2 waves) -------------
__device__ __forceinline__ double blk_sum128_d(double v, double* red) {
#pragma unroll
    for (int off = 32; off >= 1; off >>= 1) v += __shfl_down(v, off, 64);
    __syncthreads();                    // protect red[] reuse across calls
    if ((threadIdx.x & 63) == 0) red[threadIdx.x >> 6] = v;
    __syncthreads();
    return red[0] + red[1];
}

// ---------------- LN1: Fused = LN(Z + beta*Y), f64 internal -----------------
// writes Fused f32 (output), Fused f64 (ws), sq-norms f32+f64 (ws)
__global__ __launch_bounds__(128)
void ln1_kernel(const float* __restrict__ Z, const float* __restrict__ Yv,
                const float* __restrict__ betap,
                const float* __restrict__ g, const float* __restrict__ b,
                float* __restrict__ Fout, double* __restrict__ F64,
                float* __restrict__ sqf, double* __restrict__ sqd, int d)
{
    __shared__ double red[2];
    const int row = blockIdx.x, tid = threadIdx.x;
    const size_t base = (size_t)row * d + tid * 4;
    const float4 z = *(const float4*)(Z + base);
    const float4 y = *(const float4*)(Yv + base);
    const double beta = (double)(*betap);
    double s0 = (double)z.x + beta * (double)y.x;
    double s1 = (double)z.y + beta * (double)y.y;
    double s2 = (double)z.z + beta * (double)y.z;
    double s3 = (double)z.w + beta * (double)y.w;
    const double mu = blk_sum128_d(s0 + s1 + s2 + s3, red) / (double)d;
    const double q0 = s0 - mu, q1 = s1 - mu, q2 = s2 - mu, q3 = s3 - mu;
    const double var = blk_sum128_d(q0*q0 + q1*q1 + q2*q2 + q3*q3, red) / (double)d;
    const double rstd = 1.0 / sqrt(var + 1e-5);
    const float4 gg = *(const float4*)(g + tid * 4);
    const float4 bb = *(const float4*)(b + tid * 4);
    const double f0 = q0 * rstd * (double)gg.x + (double)bb.x;
    const double f1 = q1 * rstd * (double)gg.y + (double)bb.y;
    const double f2 = q2 * rstd * (double)gg.z + (double)bb.z;
    const double f3 = q3 * rstd * (double)gg.w + (double)bb.w;
    float4 fo = { (float)f0, (float)f1, (float)f2, (float)f3 };
    *(float4*)(Fout + base) = fo;
    if (F64) {
        double2 lo = { f0, f1 }, hi = { f2, f3 };
        *(double2*)(F64 + base) = lo;
        *(double2*)(F64 + base + 2) = hi;
    }
    const double sq = blk_sum128_d(f0*f0 + f1*f1 + f2*f2 + f3*f3, red);
    if (tid == 0) { sqf[row] = (float)sq; if (sqd) sqd[row] = sq; }
}

// ---------------- LN2: out = LN(X) in-place-capable, f64 internal -----------
__global__ __launch_bounds__(128)
void ln2_kernel(const float* __restrict__ X, const float* __restrict__ g,
                const float* __restrict__ b, float* __restrict__ out, int d)
{
    __shared__ double red[2];
    const int row = blockIdx.x, tid = threadIdx.x;
    const size_t base = (size_t)row * d + tid * 4;
    const float4 x = *(const float4*)(X + base);
    double s0 = x.x, s1 = x.y, s2 = x.z, s3 = x.w;
    const double mu = blk_sum128_d(s0 + s1 + s2 + s3, red) / (double)d;
    const double q0 = s0 - mu, q1 = s1 - mu, q2 = s2 - mu, q3 = s3 - mu;
    const double var = blk_sum128_d(q0*q0 + q1*q1 + q2*q2 + q3*q3, red) / (double)d;
    const double rstd = 1.0 / sqrt(var + 1e-5);
    const float4 gg = *(const float4*)(g + tid * 4);
    const float4 bb = *(const float4*)(b + tid * 4);
    float4 fo = { (float)(q0 * rstd * (double)gg.x + (double)bb.x),
                  (float)(q1 * rstd * (double)gg.y + (double)bb.y),
                  (float)(q2 * rstd * (double)gg.z + (double)bb.z),
                  (float)(q3 * rstd * (double)gg.w + (double)bb.w) };
    *(float4*)(out + base) = fo;
}

// ---------------- pass-1 fp32 distance GEMM: C = sq_i + sq_j - 2 F F^T ------
// 128x128 tile, BK=16, 256 thr, 8x8/thread. Cols split tx*4 / 64+tx*4 so LDS
// B-frag reads are only 2-way bank-aliased (free).
__global__ __launch_bounds__(256)
void gemm_d2_f32(const float* __restrict__ F, const float* __restrict__ sqf,
                 float* __restrict__ C, int Nn, int K)
{
    __shared__ float As[16][132];
    __shared__ float Bs[16][132];
    const int i0 = blockIdx.y * 128, j0 = blockIdx.x * 128;
    const int tid = threadIdx.x, ty = tid >> 4, tx = tid & 15;
    float acc[8][8];
#pragma unroll
    for (int r = 0; r < 8; ++r)
#pragma unroll
        for (int c = 0; c < 8; ++c) acc[r][c] = 0.f;

    for (int kt = 0; kt < K; kt += 16) {
#pragma unroll
        for (int l = 0; l < 2; ++l) {
            const int f = tid + l * 256;        // 512 float4s per matrix tile
            const int r = f >> 2, kq = f & 3;
            const float4 a = *(const float4*)(F + (size_t)(i0 + r) * K + kt + kq * 4);
            As[kq*4+0][r] = a.x; As[kq*4+1][r] = a.y; As[kq*4+2][r] = a.z; As[kq*4+3][r] = a.w;
            const float4 bvv = *(const float4*)(F + (size_t)(j0 + r) * K + kt + kq * 4);
            Bs[kq*4+0][r] = bvv.x; Bs[kq*4+1][r] = bvv.y; Bs[kq*4+2][r] = bvv.z; Bs[kq*4+3][r] = bvv.w;
        }
        __syncthreads();
#pragma unroll
        for (int k = 0; k < 16; ++k) {
            float av[8], bv[8];
            *(float4*)&av[0] = *(const float4*)&As[k][ty * 8];
            *(float4*)&av[4] = *(const float4*)&As[k][ty * 8 + 4];
            *(float4*)&bv[0] = *(const float4*)&Bs[k][tx * 4];
            *(float4*)&bv[4] = *(const float4*)&Bs[k][tx * 4 + 64];
#pragma unroll
            for (int r = 0; r < 8; ++r)
#pragma unroll
                for (int c = 0; c < 8; ++c)
                    acc[r][c] = fmaf(av[r], bv[c], acc[r][c]);
        }
        __syncthreads();
    }
    const float4 sj0 = *(const float4*)(sqf + j0 + tx * 4);
    const float4 sj1 = *(const float4*)(sqf + j0 + 64 + tx * 4);
#pragma unroll
    for (int r = 0; r < 8; ++r) {
        const int i = i0 + ty * 8 + r;
        const float si = sqf[i];
        float4 o0 = { (si + sj0.x) - 2.f*acc[r][0], (si + sj0.y) - 2.f*acc[r][1],
                      (si + sj0.z) - 2.f*acc[r][2], (si + sj0.w) - 2.f*acc[r][3] };
        float4 o1 = { (si + sj1.x) - 2.f*acc[r][4], (si + sj1.y) - 2.f*acc[r][5],
                      (si + sj1.z) - 2.f*acc[r][6], (si + sj1.w) - 2.f*acc[r][7] };
        *(float4*)(C + (size_t)i * Nn + j0 + tx * 4) = o0;
        *(float4*)(C + (size_t)i * Nn + j0 + 64 + tx * 4) = o1;
    }
}

// ---------------- projection GEMM: C = P W^T + bias -------------------------
__global__ __launch_bounds__(256)
void gemm_proj_f32(const float* __restrict__ A, const float* __restrict__ Bw,
                   const float* __restrict__ bias, float* __restrict__ C,
                   int M, int Nn, int K)
{
    __shared__ float As[16][132];
    __shared__ float Bs[16][132];
    const int i0 = blockIdx.y * 128, j0 = blockIdx.x * 128;
    const int tid = threadIdx.x, ty = tid >> 4, tx = tid & 15;
    float acc[8][8];
#pragma unroll
    for (int r = 0; r < 8; ++r)
#pragma unroll
        for (int c = 0; c < 8; ++c) acc[r][c] = 0.f;

    for (int kt = 0; kt < K; kt += 16) {
#pragma unroll
        for (int l = 0; l < 2; ++l) {
            const int f = tid + l * 256;
            const int r = f >> 2, kq = f & 3;
            const float4 a = *(const float4*)(A + (size_t)(i0 + r) * K + kt + kq * 4);
            As[kq*4+0][r] = a.x; As[kq*4+1][r] = a.y; As[kq*4+2][r] = a.z; As[kq*4+3][r] = a.w;
            const float4 bvv = *(const float4*)(Bw + (size_t)(j0 + r) * K + kt + kq * 4);
            Bs[kq*4+0][r] = bvv.x; Bs[kq*4+1][r] = bvv.y; Bs[kq*4+2][r] = bvv.z; Bs[kq*4+3][r] = bvv.w;
        }
        __syncthreads();
#pragma unroll
        for (int k = 0; k < 16; ++k) {
            float av[8], bv[8];
            *(float4*)&av[0] = *(const float4*)&As[k][ty * 8];
            *(float4*)&av[4] = *(const float4*)&As[k][ty * 8 + 4];
            *(float4*)&bv[0] = *(const float4*)&Bs[k][tx * 4];
            *(float4*)&bv[4] = *(const float4*)&Bs[k][tx * 4 + 64];
#pragma unroll
            for (int r = 0; r < 8; ++r)
#pragma unroll
                for (int c = 0; c < 8; ++c)
                    acc[r][c] = fmaf(av[r], bv[c], acc[r][c]);
        }
        __syncthreads();
    }
    const float4 bj0 = *(const float4*)(bias + j0 + tx * 4);
    const float4 bj1 = *(const float4*)(bias + j0 + 64 + tx * 4);
#pragma unroll
    for (int r = 0; r < 8; ++r) {
        const int i = i0 + ty * 8 + r;
        float4 o0 = { acc[r][0] + bj0.x, acc[r][1] + bj0.y, acc[r][2] + bj0.z, acc[r][3] + bj0.w };
        float4 o1 = { acc[r][4] + bj1.x, acc[r][5] + bj1.y, acc[r][6] + bj1.z, acc[r][7] + bj1.w };
        *(float4*)(C + (size_t)i * Nn + j0 + tx * 4) = o0;
        *(float4*)(C + (size_t)i * Nn + j0 + 64 + tx * 4) = o1;
    }
}

// ---------------- top-k per row + ambiguity flagging ------------------------
// Reads d2 row (fp32) from the graph region, finds k+1 smallest (tie -> lower
// index, matching lax.top_k), rewrites the row as adjacency, records nbr idx.
// If gap(16th,17th) < tau: append row to refine list and gather its f64 data.
__global__ __launch_bounds__(256)
void topk_flag(float* __restrict__ graph, int* __restrict__ nbr,
               const int* __restrict__ kp, float tau,
               const double* __restrict__ F64, const double* __restrict__ sqd,
               int* __restrict__ ctr, int* __restrict__ list,
               double* __restrict__ Aun, double* __restrict__ squn,
               int Nn, int K, int cap)
{
    __shared__ unsigned key[8192];
    __shared__ unsigned long long wred[4];
    __shared__ int sel[KMAX + 1];
    __shared__ float selval[2];
    __shared__ int myidx;
    const int row = blockIdx.x, tid = threadIdx.x;
    const int k = *kp;
    float* drow = graph + (size_t)row * Nn;

    for (int j4 = tid; j4 < (Nn >> 2); j4 += 256) {
        const float4 v = ((const float4*)drow)[j4];
        const int j = j4 * 4;
#pragma unroll
        for (int q = 0; q < 4; ++q) {
            const float fv = (q == 0) ? v.x : (q == 1) ? v.y : (q == 2) ? v.z : v.w;
            const unsigned bits = __float_as_uint(fv);
            const unsigned u = (bits & 0x80000000u) ? ~bits : (bits | 0x80000000u);
            key[j + q] = (j + q == row) ? 0xFFFFFFFFu : u;   // exclude self
        }
    }
    __syncthreads();

    const int iters = k + 1;                     // +1 to measure boundary gap
    for (int it = 0; it < iters; ++it) {
        unsigned bk = 0xFFFFFFFFu, bi = 0xFFFFFFFFu;
        for (int j = tid; j < Nn; j += 256) {
            const unsigned u = key[j];
            if (u < bk) { bk = u; bi = (unsigned)j; }
        }
        unsigned long long p = ((unsigned long long)bk << 32) | bi;
#pragma unroll
        for (int off = 32; off >= 1; off >>= 1) {
            const unsigned long long q = __shfl_down(p, off, 64);
            p = (q < p) ? q : p;
        }
        if ((tid & 63) == 0) wred[tid >> 6] = p;
        __syncthreads();
        if (tid == 0) {
            unsigned long long m = wred[0];
            for (int w2 = 1; w2 < 4; ++w2) m = (wred[w2] < m) ? wred[w2] : m;
            const int wi = (int)(m & 0xFFFFFFFFu);
            sel[it] = wi;
            key[wi] = 0xFFFFFFFFu;
            if (it >= k - 1) {                   // recover float d2 of 16th/17th
                const unsigned uk = (unsigned)(m >> 32);
                const unsigned bits = (uk & 0x80000000u) ? (uk & 0x7FFFFFFFu) : ~uk;
                selval[it - (k - 1)] = __uint_as_float(bits);
            }
        }
        __syncthreads();
    }

    // rewrite row as adjacency
    const float invk = 1.0f / (float)k;
    float4 zz = { 0.f, 0.f, 0.f, 0.f };
    float4* o4 = (float4*)drow;
    for (int j = tid; j < (Nn >> 2); j += 256) o4[j] = zz;
    __syncthreads();
    if (tid < k) {
        drow[sel[tid]] = invk;
        nbr[(size_t)row * k + tid] = sel[tid];
    }

    if (tau >= 0.f) {
        if (tid == 0) {
            const float gap = selval[1] - selval[0];
            int mi = -1;
            if (gap < tau) {
                mi = atomicAdd(ctr, 1);
                if (mi >= cap) mi = -1;          // overflow: keep pass-1 pick
            }
            if (mi >= 0) { list[mi] = row; squn[mi] = sqd[row]; }
            myidx = mi;
        }
        __syncthreads();
        const int mi = myidx;
        if (mi >= 0)
            for (int c = tid; c < K; c += 256)
                Aun[(size_t)mi * K + c] = F64[(size_t)row * K + c];
    }
}

// ---------------- fp64 refine GEMM for ambiguous rows -----------------------
// 64x64 tile, BK=16, 4x4/thread. Cd2[i][j] = sq_i + sq_j - 2 * <Aun_i, F64_j>
__global__ __launch_bounds__(256)
void gemm_d2_f64(const double* __restrict__ Aun, const double* __restrict__ F64,
                 const double* __restrict__ squn, const double* __restrict__ sq64,
                 const int* __restrict__ ctr, double* __restrict__ Cd2,
                 int Nn, int K, int cap)
{
    int count = *ctr; if (count > cap) count = cap;
    const int iu0 = blockIdx.y * 64;
    if (iu0 >= count) return;
    const int j0 = blockIdx.x * 64;
    __shared__ double As[16][68];
    __shared__ double Bs[16][68];
    const int tid = threadIdx.x, ty = tid >> 4, tx = tid & 15;
    double acc[4][4];
#pragma unroll
    for (int r = 0; r < 4; ++r)
#pragma unroll
        for (int c = 0; c < 4; ++c) acc[r][c] = 0.0;

    for (int kt = 0; kt < K; kt += 16) {
#pragma unroll
        for (int l = 0; l < 2; ++l) {
            const int f = tid + l * 256;        // 512 double2s per tile
            const int r = f >> 3, kq = f & 7;
            const double2 a = *(const double2*)(Aun + (size_t)(iu0 + r) * K + kt + kq * 2);
            As[kq*2+0][r] = a.x; As[kq*2+1][r] = a.y;
            const double2 bv = *(const double2*)(F64 + (size_t)(j0 + r) * K + kt + kq * 2);
            Bs[kq*2+0][r] = bv.x; Bs[kq*2+1][r] = bv.y;
        }
        __syncthreads();
#pragma unroll
        for (int k = 0; k < 16; ++k) {
            double av[4], bv[4];
            *(double2*)&av[0] = *(const double2*)&As[k][ty * 4];
            *(double2*)&av[2] = *(const double2*)&As[k][ty * 4 + 2];
            *(double2*)&bv[0] = *(const double2*)&Bs[k][tx * 2];
            *(double2*)&bv[2] = *(const double2*)&Bs[k][tx * 2 + 32];
#pragma unroll
            for (int r = 0; r < 4; ++r)
#pragma unroll
                for (int c = 0; c < 4; ++c)
                    acc[r][c] = fma(av[r], bv[c], acc[r][c]);
        }
        __syncthreads();
    }
#pragma unroll
    for (int r = 0; r < 4; ++r) {
        const int iu = iu0 + ty * 4 + r;
        const double si = squn[iu];
        double2 o;
        o.x = (si + sq64[j0 + tx*2])      - 2.0 * acc[r][0];
        o.y = (si + sq64[j0 + tx*2 + 1])  - 2.0 * acc[r][1];
        *(double2*)(Cd2 + (size_t)iu * Nn + j0 + tx * 2) = o;
        o.x = (si + sq64[j0 + 32 + tx*2])     - 2.0 * acc[r][2];
        o.y = (si + sq64[j0 + 32 + tx*2 + 1]) - 2.0 * acc[r][3];
        *(double2*)(Cd2 + (size_t)iu * Nn + j0 + 32 + tx * 2) = o;
    }
}

// ---------------- fp64 top-k merge for refined rows (global-mem scan) -------
__global__ __launch_bounds__(256)
void merge_topk(double* __restrict__ Cd2, const int* __restrict__ list,
                const int* __restrict__ ctr, const int* __restrict__ kp,
                float* __restrict__ graph, int* __restrict__ nbr, int Nn, int cap)
{
    int count = *ctr; if (count > cap) count = cap;
    const int i = blockIdx.x;
    if (i >= count) return;
    __shared__ unsigned long long wredk[4];
    __shared__ unsigned wredi[4];
    __shared__ int sel[KMAX];
    const int row = list[i];
    const int k = *kp;
    const int tid = threadIdx.x;
    double* dr = Cd2 + (size_t)i * Nn;

    for (int it = 0; it < k; ++it) {
        unsigned long long bk = ~0ull; unsigned bi = 0xFFFFFFFFu;
        for (int j = tid; j < Nn; j += 256) {
            if (j == row) continue;
            const unsigned long long bits = (unsigned long long)__double_as_longlong(dr[j]);
            const unsigned long long u =
                (bits & 0x8000000000000000ull) ? ~bits : (bits | 0x8000000000000000ull);
            if (u < bk) { bk = u; bi = (unsigned)j; }
        }
#pragma unroll
        for (int off = 32; off >= 1; off >>= 1) {
            const unsigned long long qk = __shfl_down(bk, off, 64);
            const unsigned qi = __shfl_down(bi, off, 64);
            if (qk < bk || (qk == bk && qi < bi)) { bk = qk; bi = qi; }
        }
        if ((tid & 63) == 0) { wredk[tid >> 6] = bk; wredi[tid >> 6] = bi; }
        __syncthreads();
        if (tid == 0) {
            unsigned long long mk = wredk[0]; unsigned mi = wredi[0];
            for (int w2 = 1; w2 < 4; ++w2)
                if (wredk[w2] < mk || (wredk[w2] == mk && wredi[w2] < mi)) { mk = wredk[w2]; mi = wredi[w2]; }
            sel[it] = (int)mi;
            dr[mi] = __longlong_as_double(0x7FF0000000000000ll);   // consume: +inf
        }
        __syncthreads();
    }
    const float invk = 1.0f / (float)k;
    float* drow = graph + (size_t)row * Nn;
    float4 zz = { 0.f, 0.f, 0.f, 0.f };
    for (int j = tid; j < (Nn >> 2); j += 256) ((float4*)drow)[j] = zz;
    __syncthreads();
    if (tid < k) {
        drow[sel[tid]] = invk;
        nbr[(size_t)row * k + tid] = sel[tid];
    }
}

// ---------------- gather: P[row] = mean of k neighbor rows ------------------
__global__ __launch_bounds__(128)
void gather_kernel(const float* __restrict__ F, const int* __restrict__ nbr,
                   const int* __restrict__ kp, float* __restrict__ P, int d)
{
    const int row = blockIdx.x, tid = threadIdx.x;
    const int k = *kp;
    const int* nb = nbr + (size_t)row * k;
    float ax = 0.f, ay = 0.f, az = 0.f, aw = 0.f;
    for (int t = 0; t < k; ++t) {
        const int j = nb[t];
        const float4 v = *(const float4*)(F + (size_t)j * d + tid * 4);
        ax += v.x; ay += v.y; az += v.z; aw += v.w;
    }
    const float invk = 1.0f / (float)k;   // 1/16: exact pow2, scale order-safe
    float4 o = { ax * invk, ay * invk, az * invk, aw * invk };
    *(float4*)(P + (size_t)row * d + tid * 4) = o;
}

// ---------------- host ------------------------------------------------------
extern "C" void kernel_launch(void* const* d_in, const int* in_sizes, int n_in,
                              void* d_out, int out_size, void* d_ws, size_t ws_size,
                              hipStream_t stream)
{
    const float* Z     = (const float*)d_in[0];
    const float* Yv    = (const float*)d_in[1];
    const float* g1    = (const float*)d_in[2];
    const float* b1    = (const float*)d_in[3];
    const float* W     = (const float*)d_in[4];
    const float* bias  = (const float*)d_in[5];
    const float* g2    = (const float*)d_in[6];
    const float* b2    = (const float*)d_in[7];
    const int*   kp    = (const int*)d_in[8];
    const float* betap = (const float*)d_in[9];
    const int d = in_sizes[2];          // 512
    const int N = in_sizes[0] / d;      // 8192

    float* Fused  = (float*)d_out;
    float* graph  = Fused + (size_t)N * d;
    float* hidden = graph + (size_t)N * N;

    char* w = (char*)d_ws;
    size_t off = 0;
    auto alloc = [&](size_t bytes) -> void* {
        void* p = (void*)(w + off);
        off += (bytes + 255) & ~(size_t)255;
        return p;
    };
    double* F64  = (double*)alloc((size_t)N * d * 8);   // 32 MB
    double* sqd  = (double*)alloc((size_t)N * 8);
    float*  sqf  = (float*) alloc((size_t)N * 4);
    int*    nbr  = (int*)   alloc((size_t)N * KMAX * 4);
    int*    ctr  = (int*)   alloc(256);
    int*    list = (int*)   alloc((size_t)CAP * 4);
    double* squn = (double*)alloc((size_t)CAP * 8);
    double* Aun  = (double*)alloc((size_t)CAP * d * 8); // 1 MB
    double* Cd2  = (double*)alloc((size_t)CAP * N * 8); // 16 MB
    float*  P    = (float*) alloc((size_t)N * d * 4);   // 16 MB
    const bool full = (off <= ws_size);
    if (!full) {  // degraded: fp32-only selection, no refinement
        off = 0;
        sqf = (float*)alloc((size_t)N * 4);
        nbr = (int*)  alloc((size_t)N * KMAX * 4);
        P   = (float*)alloc((size_t)N * d * 4);
        F64 = nullptr; sqd = nullptr; ctr = nullptr;
        list = nullptr; squn = nullptr; Aun = nullptr; Cd2 = nullptr;
    }

    if (full) hipMemsetAsync(ctr, 0, 256, stream);
    ln1_kernel<<<N, 128, 0, stream>>>(Z, Yv, betap, g1, b1, Fused, F64, sqf, sqd, d);
    dim3 gg(N / 128, N / 128);
    gemm_d2_f32<<<gg, 256, 0, stream>>>(Fused, sqf, graph, N, d);
    topk_flag<<<N, 256, 0, stream>>>(graph, nbr, kp, full ? TAU : -1.0f,
                                     F64, sqd, ctr, list, Aun, squn, N, d, CAP);
    if (full) {
        dim3 gr(N / 64, CAP / 64);
        gemm_d2_f64<<<gr, 256, 0, stream>>>(Aun, F64, squn, sqd, ctr, Cd2, N, d, CAP);
        merge_topk<<<CAP, 256, 0, stream>>>(Cd2, list, ctr, kp, graph, nbr, N, CAP);
    }
    gather_kernel<<<N, 128, 0, stream>>>(Fused, nbr, kp, P, d);
    dim3 gp(d / 128, N / 128);
    gemm_proj_f32<<<gp, 256, 0, stream>>>(P, W, bias, hidden, N, d, d);
    ln2_kernel<<<N, 128, 0, stream>>>(hidden, g2, b2, hidden, d);
}

// Round 10
// 1188.069 us; speedup vs baseline: 1.4421x; 1.4421x over previous
//
#include <hip/hip_runtime.h>

// GraphRefiner: Fused = LN1(Z + beta*Y); graph = exact kNN(k) row-normalized
// adjacency from Fused; hidden = LN2(mean_nbr(Fused) @ W^T + bias).
//
// Pass-1 distances: fp16 split-2 MFMA GEMM with full cross terms:
//   F = H + L (hi/lo fp16). F.F' = HH' + LH' + HL' (+LL' ~ 1e-7, dropped).
//   One GEMM, K_eff = 1536: A-halves [H|L|H], B-halves [H|H|L].
// Rows with ambiguous 16/17 boundary (pass-1 gap < TAU) are re-resolved with
// an fp64-accumulated GEMM on the f32 Fused (exact on the rounded data).
// TAU=0.01 is the round-2-validated net (2*err_pass1 ~ 4e-4, 25x margin).

#define TAU 0.01f
#define CAP 256      // max refined rows
#define KMAX 64

typedef _Float16 half8 __attribute__((ext_vector_type(8)));
typedef float f32x4 __attribute__((ext_vector_type(4)));

// ---------------- block-wide f64 sum over 128 threads (2 waves) -------------
__device__ __forceinline__ double blk_sum128_d(double v, double* red) {
#pragma unroll
    for (int off = 32; off >= 1; off >>= 1) v += __shfl_down(v, off, 64);
    __syncthreads();                    // protect red[] reuse across calls
    if ((threadIdx.x & 63) == 0) red[threadIdx.x >> 6] = v;
    __syncthreads();
    return red[0] + red[1];
}

// ---------------- LN1: Fused = LN(Z + beta*Y), f64 internal -----------------
__global__ __launch_bounds__(128)
void ln1_kernel(const float* __restrict__ Z, const float* __restrict__ Yv,
                const float* __restrict__ betap,
                const float* __restrict__ g, const float* __restrict__ b,
                float* __restrict__ Fout, _Float16* __restrict__ G,
                float* __restrict__ sqf, double* __restrict__ sqd, int d)
{
    __shared__ double red[2];
    const int row = blockIdx.x, tid = threadIdx.x;
    const size_t base = (size_t)row * d + tid * 4;
    const float4 z = *(const float4*)(Z + base);
    const float4 y = *(const float4*)(Yv + base);
    const double beta = (double)(*betap);
    double s0 = (double)z.x + beta * (double)y.x;
    double s1 = (double)z.y + beta * (double)y.y;
    double s2 = (double)z.z + beta * (double)y.z;
    double s3 = (double)z.w + beta * (double)y.w;
    const double mu = blk_sum128_d(s0 + s1 + s2 + s3, red) / (double)d;
    const double q0 = s0 - mu, q1 = s1 - mu, q2 = s2 - mu, q3 = s3 - mu;
    const double var = blk_sum128_d(q0*q0 + q1*q1 + q2*q2 + q3*q3, red) / (double)d;
    const double rstd = 1.0 / sqrt(var + 1e-5);
    const float4 gg = *(const float4*)(g + tid * 4);
    const float4 bb = *(const float4*)(b + tid * 4);
    float4 fo = { (float)(q0 * rstd * (double)gg.x + (double)bb.x),
                  (float)(q1 * rstd * (double)gg.y + (double)bb.y),
                  (float)(q2 * rstd * (double)gg.z + (double)bb.z),
                  (float)(q3 * rstd * (double)gg.w + (double)bb.w) };
    *(float4*)(Fout + base) = fo;

    // fp16 split-2: fo = h + l, |l| <= |fo|*2^-11, combined repr err ~2^-22
    _Float16 h0 = (_Float16)fo.x, h1 = (_Float16)fo.y,
             h2 = (_Float16)fo.z, h3 = (_Float16)fo.w;
    _Float16 l0 = (_Float16)(fo.x - (float)h0), l1 = (_Float16)(fo.y - (float)h1),
             l2 = (_Float16)(fo.z - (float)h2), l3 = (_Float16)(fo.w - (float)h3);
    _Float16* grow = G + (size_t)row * (2 * d);
    typedef _Float16 half4v __attribute__((ext_vector_type(4)));
    half4v hv = { h0, h1, h2, h3 }, lv = { l0, l1, l2, l3 };
    *(half4v*)(grow + tid * 4) = hv;
    *(half4v*)(grow + d + tid * 4) = lv;

    // norms of the ROUNDED f32 values (f64-exact): refinement then matches an
    // fp64 reference on the f32 data.
    const double f0 = (double)fo.x, f1 = (double)fo.y,
                 f2 = (double)fo.z, f3 = (double)fo.w;
    const double sq = blk_sum128_d(f0*f0 + f1*f1 + f2*f2 + f3*f3, red);
    if (tid == 0) { sqf[row] = (float)sq; if (sqd) sqd[row] = sq; }
}

// ---------------- LN2: out = LN(X) in-place-capable, f64 internal -----------
__global__ __launch_bounds__(128)
void ln2_kernel(const float* __restrict__ X, const float* __restrict__ g,
                const float* __restrict__ b, float* __restrict__ out, int d)
{
    __shared__ double red[2];
    const int row = blockIdx.x, tid = threadIdx.x;
    const size_t base = (size_t)row * d + tid * 4;
    const float4 x = *(const float4*)(X + base);
    double s0 = x.x, s1 = x.y, s2 = x.z, s3 = x.w;
    const double mu = blk_sum128_d(s0 + s1 + s2 + s3, red) / (double)d;
    const double q0 = s0 - mu, q1 = s1 - mu, q2 = s2 - mu, q3 = s3 - mu;
    const double var = blk_sum128_d(q0*q0 + q1*q1 + q2*q2 + q3*q3, red) / (double)d;
    const double rstd = 1.0 / sqrt(var + 1e-5);
    const float4 gg = *(const float4*)(g + tid * 4);
    const float4 bb = *(const float4*)(b + tid * 4);
    float4 fo = { (float)(q0 * rstd * (double)gg.x + (double)bb.x),
                  (float)(q1 * rstd * (double)gg.y + (double)bb.y),
                  (float)(q2 * rstd * (double)gg.z + (double)bb.z),
                  (float)(q3 * rstd * (double)gg.w + (double)bb.w) };
    *(float4*)(out + base) = fo;
}

// ---------------- pass-1 MFMA distance GEMM ---------------------------------
// C[i][j] = sqf[i] + sqf[j] - 2 * sum_t A(t).B(t),  G: [N][1024] fp16 = [H|L].
// 48 K-steps of BK=32: t<16: A=H,B=H; 16<=t<32: A=L,B=H; t>=32: A=H,B=L.
// 128x128 tile, 4 waves (2x2), 4x4 frags of 16x16x32_f16 each.
// LDS [128 rows][64B] dbuf, staged via global_load_lds(16B) with source-granule
// swizzle slot = gs ^ ((row>>1)&3) (involution; conflict-free b128 reads).
__global__ __launch_bounds__(256)
void gemm_d2_mfma(const _Float16* __restrict__ G, const float* __restrict__ sqf,
                  float* __restrict__ C, int Nn)
{
    __shared__ __align__(16) char smem[2][2][8192];   // [buf][A/B][bytes]
    const int tid = threadIdx.x;
    const int lane = tid & 63, w = tid >> 6;
    const int wr = w >> 1, wc = w & 1;

    int bid = blockIdx.x;
    const int nwg = gridDim.x;
    if ((nwg & 7) == 0) bid = (bid & 7) * (nwg >> 3) + (bid >> 3);  // XCD swizzle
    const int nt = Nn >> 7;
    const int bi = bid / nt, bj = bid % nt;
    const int i0 = bi * 128, j0 = bj * 128;

    f32x4 acc[4][4] = {};

    auto ktA = [](int t) { return t < 16 ? t * 32 : (t < 32 ? 512 + (t - 16) * 32 : (t - 32) * 32); };
    auto ktB = [](int t) { return t < 16 ? t * 32 : (t < 32 ? (t - 16) * 32 : 512 + (t - 32) * 32); };

    auto stage = [&](const _Float16* rowbase, int kt, char* ldsb) {
#pragma unroll
        for (int q = 0; q < 2; ++q) {
            const int gi = q * 256 + tid;           // granule 0..511
            const int r = gi >> 2, s = gi & 3;
            const int gs = s ^ ((r >> 1) & 3);      // source granule (swizzle)
            const _Float16* src = rowbase + (size_t)r * 1024 + kt + gs * 8;
            char* dst = ldsb + q * 4096 + w * 1024; // wave-uniform; HW adds lane*16
            __builtin_amdgcn_global_load_lds(
                (const __attribute__((address_space(1))) unsigned int*)(const void*)src,
                (__attribute__((address_space(3))) unsigned int*)(void*)dst,
                16, 0, 0);
        }
    };

    const _Float16* Arow = G + (size_t)i0 * 1024;
    const _Float16* Brow = G + (size_t)j0 * 1024;

    stage(Arow, 0, smem[0][0]);
    stage(Brow, 0, smem[0][1]);
    __syncthreads();                                // drains vmcnt

    const int gsl = lane >> 4;                      // k-granule 0..3
    const int rl = lane & 15;

    for (int t = 0; t < 48; ++t) {
        const int cur = t & 1;
        if (t + 1 < 48) {
            stage(Arow, ktA(t + 1), smem[cur ^ 1][0]);
            stage(Brow, ktB(t + 1), smem[cur ^ 1][1]);
        }
        half8 af[4], bf[4];
#pragma unroll
        for (int m = 0; m < 4; ++m) {
            const int ra = wr * 64 + m * 16 + rl;
            const int slot = gsl ^ ((ra >> 1) & 3);
            af[m] = *(const half8*)(smem[cur][0] + ra * 64 + slot * 16);
        }
#pragma unroll
        for (int n = 0; n < 4; ++n) {
            const int rb = wc * 64 + n * 16 + rl;
            const int slot = gsl ^ ((rb >> 1) & 3);
            bf[n] = *(const half8*)(smem[cur][1] + rb * 64 + slot * 16);
        }
#pragma unroll
        for (int m = 0; m < 4; ++m)
#pragma unroll
            for (int n = 0; n < 4; ++n)
                acc[m][n] = __builtin_amdgcn_mfma_f32_16x16x32_f16(
                    af[m], bf[n], acc[m][n], 0, 0, 0);
        __syncthreads();
    }

    // epilogue: C/D layout col = lane&15, row = (lane>>4)*4 + reg
    const int cb = rl, rq = lane >> 4;
    float sj[4];
#pragma unroll
    for (int n = 0; n < 4; ++n) sj[n] = sqf[j0 + wc * 64 + n * 16 + cb];
#pragma unroll
    for (int m = 0; m < 4; ++m) {
#pragma unroll
        for (int q = 0; q < 4; ++q) {
            const int i = i0 + wr * 64 + m * 16 + rq * 4 + q;
            const float si = sqf[i];
            float* crow = C + (size_t)i * Nn + j0 + wc * 64 + cb;
#pragma unroll
            for (int n = 0; n < 4; ++n)
                crow[n * 16] = (si + sj[n]) - 2.0f * acc[m][n][q];
        }
    }
}

// ---------------- projection GEMM: C = P W^T + bias -------------------------
__global__ __launch_bounds__(256)
void gemm_proj_f32(const float* __restrict__ A, const float* __restrict__ Bw,
                   const float* __restrict__ bias, float* __restrict__ C,
                   int M, int Nn, int K)
{
    __shared__ float As[16][132];
    __shared__ float Bs[16][132];
    const int i0 = blockIdx.y * 128, j0 = blockIdx.x * 128;
    const int tid = threadIdx.x, ty = tid >> 4, tx = tid & 15;
    float acc[8][8];
#pragma unroll
    for (int r = 0; r < 8; ++r)
#pragma unroll
        for (int c = 0; c < 8; ++c) acc[r][c] = 0.f;

    for (int kt = 0; kt < K; kt += 16) {
#pragma unroll
        for (int l = 0; l < 2; ++l) {
            const int f = tid + l * 256;
            const int r = f >> 2, kq = f & 3;
            const float4 a = *(const float4*)(A + (size_t)(i0 + r) * K + kt + kq * 4);
            As[kq*4+0][r] = a.x; As[kq*4+1][r] = a.y; As[kq*4+2][r] = a.z; As[kq*4+3][r] = a.w;
            const float4 bvv = *(const float4*)(Bw + (size_t)(j0 + r) * K + kt + kq * 4);
            Bs[kq*4+0][r] = bvv.x; Bs[kq*4+1][r] = bvv.y; Bs[kq*4+2][r] = bvv.z; Bs[kq*4+3][r] = bvv.w;
        }
        __syncthreads();
#pragma unroll
        for (int k = 0; k < 16; ++k) {
            float av[8], bv[8];
            *(float4*)&av[0] = *(const float4*)&As[k][ty * 8];
            *(float4*)&av[4] = *(const float4*)&As[k][ty * 8 + 4];
            *(float4*)&bv[0] = *(const float4*)&Bs[k][tx * 4];
            *(float4*)&bv[4] = *(const float4*)&Bs[k][tx * 4 + 64];
#pragma unroll
            for (int r = 0; r < 8; ++r)
#pragma unroll
                for (int c = 0; c < 8; ++c)
                    acc[r][c] = fmaf(av[r], bv[c], acc[r][c]);
        }
        __syncthreads();
    }
    const float4 bj0 = *(const float4*)(bias + j0 + tx * 4);
    const float4 bj1 = *(const float4*)(bias + j0 + 64 + tx * 4);
#pragma unroll
    for (int r = 0; r < 8; ++r) {
        const int i = i0 + ty * 8 + r;
        float4 o0 = { acc[r][0] + bj0.x, acc[r][1] + bj0.y, acc[r][2] + bj0.z, acc[r][3] + bj0.w };
        float4 o1 = { acc[r][4] + bj1.x, acc[r][5] + bj1.y, acc[r][6] + bj1.z, acc[r][7] + bj1.w };
        *(float4*)(C + (size_t)i * Nn + j0 + tx * 4) = o0;
        *(float4*)(C + (size_t)i * Nn + j0 + 64 + tx * 4) = o1;
    }
}

// ---------------- top-k per row + ambiguity flagging ------------------------
__global__ __launch_bounds__(256)
void topk_flag(float* __restrict__ graph, int* __restrict__ nbr,
               const int* __restrict__ kp, float tau,
               int* __restrict__ ctr, int* __restrict__ list, int Nn, int cap)
{
    __shared__ unsigned key[8192];
    __shared__ unsigned long long wred[4];
    __shared__ int sel[KMAX + 1];
    __shared__ float selval[2];
    const int row = blockIdx.x, tid = threadIdx.x;
    const int k = *kp;
    float* drow = graph + (size_t)row * Nn;

    for (int j4 = tid; j4 < (Nn >> 2); j4 += 256) {
        const float4 v = ((const float4*)drow)[j4];
        const int j = j4 * 4;
#pragma unroll
        for (int q = 0; q < 4; ++q) {
            const float fv = (q == 0) ? v.x : (q == 1) ? v.y : (q == 2) ? v.z : v.w;
            const unsigned bits = __float_as_uint(fv);
            const unsigned u = (bits & 0x80000000u) ? ~bits : (bits | 0x80000000u);
            key[j + q] = (j + q == row) ? 0xFFFFFFFFu : u;   // exclude self
        }
    }
    __syncthreads();

    const int iters = k + 1;                     // +1 to measure boundary gap
    for (int it = 0; it < iters; ++it) {
        unsigned bk = 0xFFFFFFFFu, bi = 0xFFFFFFFFu;
        for (int j = tid; j < Nn; j += 256) {
            const unsigned u = key[j];
            if (u < bk) { bk = u; bi = (unsigned)j; }
        }
        unsigned long long p = ((unsigned long long)bk << 32) | bi;
#pragma unroll
        for (int off = 32; off >= 1; off >>= 1) {
            const unsigned long long q = __shfl_down(p, off, 64);
            p = (q < p) ? q : p;
        }
        if ((tid & 63) == 0) wred[tid >> 6] = p;
        __syncthreads();
        if (tid == 0) {
            unsigned long long m = wred[0];
            for (int w2 = 1; w2 < 4; ++w2) m = (wred[w2] < m) ? wred[w2] : m;
            const int wi = (int)(m & 0xFFFFFFFFu);
            sel[it] = wi;
            key[wi] = 0xFFFFFFFFu;
            if (it >= k - 1) {                   // recover float d2 of 16th/17th
                const unsigned uk = (unsigned)(m >> 32);
                const unsigned bits = (uk & 0x80000000u) ? (uk & 0x7FFFFFFFu) : ~uk;
                selval[it - (k - 1)] = __uint_as_float(bits);
            }
        }
        __syncthreads();
    }

    // rewrite row as adjacency
    const float invk = 1.0f / (float)k;
    float4 zz = { 0.f, 0.f, 0.f, 0.f };
    float4* o4 = (float4*)drow;
    for (int j = tid; j < (Nn >> 2); j += 256) o4[j] = zz;
    __syncthreads();
    if (tid < k) {
        drow[sel[tid]] = invk;
        nbr[(size_t)row * k + tid] = sel[tid];
    }

    if (tau >= 0.f && tid == 0) {
        const float gap = selval[1] - selval[0];
        if (gap < tau) {
            const int mi = atomicAdd(ctr, 1);
            if (mi < cap) list[mi] = row;        // overflow: keep pass-1 pick
        }
    }
}

// ---------------- fp64 refine GEMM for ambiguous rows -----------------------
// Cd2[iu][j] = sqd[list[iu]] + sqd[j] - 2 * <F_list[iu], F_j>, f64-accumulated
// from the f32 Fused (exact arithmetic on the rounded data).
__global__ __launch_bounds__(256)
void refine_d2(const float* __restrict__ Fp, const double* __restrict__ sqd,
               const int* __restrict__ list, const int* __restrict__ ctr,
               double* __restrict__ Cd2, int Nn, int K, int cap)
{
    int count = *ctr; if (count > cap) count = cap;
    const int iu0 = blockIdx.y * 64;
    if (iu0 >= count) return;
    const int j0 = blockIdx.x * 64;
    __shared__ double As[16][68];
    __shared__ double Bs[16][68];
    __shared__ int arows[64];
    __shared__ double srow[64];
    const int tid = threadIdx.x, ty = tid >> 4, tx = tid & 15;
    if (tid < 64) {
        const int iu = iu0 + tid;
        const int rr = list[iu < count ? iu : count - 1];
        arows[tid] = rr;
        srow[tid] = sqd[rr];
    }
    __syncthreads();
    double acc[4][4];
#pragma unroll
    for (int r = 0; r < 4; ++r)
#pragma unroll
        for (int c = 0; c < 4; ++c) acc[r][c] = 0.0;

    for (int kt = 0; kt < K; kt += 16) {
#pragma unroll
        for (int l = 0; l < 2; ++l) {
            const int f = tid + l * 256;        // 512 float2s per tile
            const int r = f >> 3, kq = f & 7;
            const float2 a = *(const float2*)(Fp + (size_t)arows[r] * K + kt + kq * 2);
            As[kq*2+0][r] = (double)a.x; As[kq*2+1][r] = (double)a.y;
            const float2 bvv = *(const float2*)(Fp + (size_t)(j0 + r) * K + kt + kq * 2);
            Bs[kq*2+0][r] = (double)bvv.x; Bs[kq*2+1][r] = (double)bvv.y;
        }
        __syncthreads();
#pragma unroll
        for (int k = 0; k < 16; ++k) {
            double av[4], bv[4];
            *(double2*)&av[0] = *(const double2*)&As[k][ty * 4];
            *(double2*)&av[2] = *(const double2*)&As[k][ty * 4 + 2];
            *(double2*)&bv[0] = *(const double2*)&Bs[k][tx * 2];
            *(double2*)&bv[2] = *(const double2*)&Bs[k][tx * 2 + 32];
#pragma unroll
            for (int r = 0; r < 4; ++r)
#pragma unroll
                for (int c = 0; c < 4; ++c)
                    acc[r][c] = fma(av[r], bv[c], acc[r][c]);
        }
        __syncthreads();
    }
#pragma unroll
    for (int r = 0; r < 4; ++r) {
        const int iu = iu0 + ty * 4 + r;
        const double si = srow[ty * 4 + r];
        double2 o;
        o.x = (si + sqd[j0 + tx*2])      - 2.0 * acc[r][0];
        o.y = (si + sqd[j0 + tx*2 + 1])  - 2.0 * acc[r][1];
        *(double2*)(Cd2 + (size_t)iu * Nn + j0 + tx * 2) = o;
        o.x = (si + sqd[j0 + 32 + tx*2])     - 2.0 * acc[r][2];
        o.y = (si + sqd[j0 + 32 + tx*2 + 1]) - 2.0 * acc[r][3];
        *(double2*)(Cd2 + (size_t)iu * Nn + j0 + 32 + tx * 2) = o;
    }
}

// ---------------- fp64 top-k merge for refined rows -------------------------
__global__ __launch_bounds__(256)
void merge_topk(double* __restrict__ Cd2, const int* __restrict__ list,
                const int* __restrict__ ctr, const int* __restrict__ kp,
                float* __restrict__ graph, int* __restrict__ nbr, int Nn, int cap)
{
    int count = *ctr; if (count > cap) count = cap;
    const int i = blockIdx.x;
    if (i >= count) return;
    __shared__ unsigned long long wredk[4];
    __shared__ unsigned wredi[4];
    __shared__ int sel[KMAX];
    const int row = list[i];
    const int k = *kp;
    const int tid = threadIdx.x;
    double* dr = Cd2 + (size_t)i * Nn;

    for (int it = 0; it < k; ++it) {
        unsigned long long bk = ~0ull; unsigned bi = 0xFFFFFFFFu;
        for (int j = tid; j < Nn; j += 256) {
            if (j == row) continue;
            const unsigned long long bits = (unsigned long long)__double_as_longlong(dr[j]);
            const unsigned long long u =
                (bits & 0x8000000000000000ull) ? ~bits : (bits | 0x8000000000000000ull);
            if (u < bk) { bk = u; bi = (unsigned)j; }
        }
#pragma unroll
        for (int off = 32; off >= 1; off >>= 1) {
            const unsigned long long qk = __shfl_down(bk, off, 64);
            const unsigned qi = __shfl_down(bi, off, 64);
            if (qk < bk || (qk == bk && qi < bi)) { bk = qk; bi = qi; }
        }
        if ((tid & 63) == 0) { wredk[tid >> 6] = bk; wredi[tid >> 6] = bi; }
        __syncthreads();
        if (tid == 0) {
            unsigned long long mk = wredk[0]; unsigned mi = wredi[0];
            for (int w2 = 1; w2 < 4; ++w2)
                if (wredk[w2] < mk || (wredk[w2] == mk && wredi[w2] < mi)) { mk = wredk[w2]; mi = wredi[w2]; }
            sel[it] = (int)mi;
            dr[mi] = __longlong_as_double(0x7FF0000000000000ll);   // consume: +inf
        }
        __syncthreads();
    }
    const float invk = 1.0f / (float)k;
    float* drow = graph + (size_t)row * Nn;
    float4 zz = { 0.f, 0.f, 0.f, 0.f };
    for (int j = tid; j < (Nn >> 2); j += 256) ((float4*)drow)[j] = zz;
    __syncthreads();
    if (tid < k) {
        drow[sel[tid]] = invk;
        nbr[(size_t)row * k + tid] = sel[tid];
    }
}

// ---------------- gather: P[row] = mean of k neighbor rows ------------------
__global__ __launch_bounds__(128)
void gather_kernel(const float* __restrict__ F, const int* __restrict__ nbr,
                   const int* __restrict__ kp, float* __restrict__ P, int d)
{
    const int row = blockIdx.x, tid = threadIdx.x;
    const int k = *kp;
    const int* nb = nbr + (size_t)row * k;
    float ax = 0.f, ay = 0.f, az = 0.f, aw = 0.f;
    for (int t = 0; t < k; ++t) {
        const int j = nb[t];
        const float4 v = *(const float4*)(F + (size_t)j * d + tid * 4);
        ax += v.x; ay += v.y; az += v.z; aw += v.w;
    }
    const float invk = 1.0f / (float)k;   // 1/16: exact pow2
    float4 o = { ax * invk, ay * invk, az * invk, aw * invk };
    *(float4*)(P + (size_t)row * d + tid * 4) = o;
}

// ---------------- host ------------------------------------------------------
extern "C" void kernel_launch(void* const* d_in, const int* in_sizes, int n_in,
                              void* d_out, int out_size, void* d_ws, size_t ws_size,
                              hipStream_t stream)
{
    const float* Z     = (const float*)d_in[0];
    const float* Yv    = (const float*)d_in[1];
    const float* g1    = (const float*)d_in[2];
    const float* b1    = (const float*)d_in[3];
    const float* W     = (const float*)d_in[4];
    const float* bias  = (const float*)d_in[5];
    const float* g2    = (const float*)d_in[6];
    const float* b2    = (const float*)d_in[7];
    const int*   kp    = (const int*)d_in[8];
    const float* betap = (const float*)d_in[9];
    const int d = in_sizes[2];          // 512
    const int N = in_sizes[0] / d;      // 8192

    float* Fused  = (float*)d_out;
    float* graph  = Fused + (size_t)N * d;
    float* hidden = graph + (size_t)N * N;

    char* w = (char*)d_ws;
    size_t off = 0;
    auto alloc = [&](size_t bytes) -> void* {
        void* p = (void*)(w + off);
        off += (bytes + 255) & ~(size_t)255;
        return p;
    };
    _Float16* G  = (_Float16*)alloc((size_t)N * d * 2 * 2); // 16 MB (hi|lo)
    double* sqd  = (double*)alloc((size_t)N * 8);
    float*  sqf  = (float*) alloc((size_t)N * 4);
    int*    nbr  = (int*)   alloc((size_t)N * KMAX * 4);    // 2 MB
    int*    ctr  = (int*)   alloc(256);
    int*    list = (int*)   alloc((size_t)CAP * 4);
    double* Cd2  = (double*)alloc((size_t)CAP * N * 8);     // 16 MB
    float*  P    = (float*) alloc((size_t)N * d * 4);       // 16 MB
    const bool full = (off <= ws_size);
    if (!full) {  // degraded: fp16-split pass-1 only, no fp64 refinement
        off = 0;
        G   = (_Float16*)alloc((size_t)N * d * 2 * 2);
        sqf = (float*)alloc((size_t)N * 4);
        nbr = (int*)  alloc((size_t)N * KMAX * 4);
        P   = (float*)alloc((size_t)N * d * 4);
        sqd = nullptr; ctr = nullptr; list = nullptr; Cd2 = nullptr;
    }

    if (full) hipMemsetAsync(ctr, 0, 256, stream);
    ln1_kernel<<<N, 128, 0, stream>>>(Z, Yv, betap, g1, b1, Fused, G, sqf, sqd, d);
    const int nt = N / 128;
    gemm_d2_mfma<<<nt * nt, 256, 0, stream>>>(G, sqf, graph, N);
    topk_flag<<<N, 256, 0, stream>>>(graph, nbr, kp, full ? TAU : -1.0f,
                                     ctr, list, N, CAP);
    if (full) {
        dim3 gr(N / 64, CAP / 64);
        refine_d2<<<gr, 256, 0, stream>>>(Fused, sqd, list, ctr, Cd2, N, d, CAP);
        merge_topk<<<CAP, 256, 0, stream>>>(Cd2, list, ctr, kp, graph, nbr, N, CAP);
    }
    gather_kernel<<<N, 128, 0, stream>>>(Fused, nbr, kp, P, d);
    dim3 gp(d / 128, N / 128);
    gemm_proj_f32<<<gp, 256, 0, stream>>>(P, W, bias, hidden, N, d, d);
    ln2_kernel<<<N, 128, 0, stream>>>(hidden, g2, b2, hidden, d);
}